// Round 2
// baseline (2591.400 us; speedup 1.0000x reference)
//
#include <hip/hip_runtime.h>
#include <math.h>

// Sinkhorn regularized transport, B=8, m=n=1024, fp32, 100 iterations.
//
// Persistent cooperative kernel, round 2: atomic-free reduction tree.
//  - 256 blocks (1/CU), 32 blocks per batch; block keeps its 32 rows of
//    K = exp(-10*min(M,5)) resident in LDS (stride 1028: 16B-aligned, skewed).
//  - Per iteration:
//      phase A: partial[j] = sum_{own rows i} K[i][j]*u_i  -> plain float4
//               store into per-block slot part[b][g][0..1023] (no atomics).
//      barrier 1 (per batch, agent-scope counter + fences).
//      owner:   thread t<32 of block g sums part[b][*][32g+t] (32 coalesced
//               128B loads, pipelined), v_j = c/y_j, stores v[b][32g+t].
//      barrier 2.
//      all:     load v (float4/thread) -> LDS; phase B: z_i = K_rows . v,
//               u_i = r/z_i (block-local).
//  - Single-buffered part/v is race-free: writes of epoch t+1 happen only
//    after the barrier that proves all reads of epoch t completed.
//  - Round-1 evidence: atomicAdd reduce ran at the L3 coherence point with
//    ~512 same-line RMWs serializing per iteration (WRITE_SIZE 450MB,
//    13us/iter). This version has zero contended atomics.

#define B_    8
#define N_    1024
#define G_    32          // blocks per batch
#define RPB   32          // rows per block
#define KSTR  1028        // LDS row stride (floats): 16B aligned, bank skew 4
#define NITER 100
#define TPB   256
#define LMB   10.0f
#define MAXD  5.0f

#define LDS_FLOATS (RPB * KSTR + N_ + RPB)

__device__ __forceinline__ void batch_barrier(int* cnt, int target) {
    __syncthreads();   // all waves' stores drained (vmcnt(0) before s_barrier)
    if (threadIdx.x == 0) {
        __threadfence();                                   // release: wbl2
        __hip_atomic_fetch_add(cnt, 1, __ATOMIC_RELAXED, __HIP_MEMORY_SCOPE_AGENT);
        while (__hip_atomic_load(cnt, __ATOMIC_RELAXED, __HIP_MEMORY_SCOPE_AGENT) < target) {
            __builtin_amdgcn_s_sleep(1);
        }
        __threadfence();                                   // acquire: inv L1/L2
    }
    __syncthreads();
}

__global__ void __launch_bounds__(TPB)
sinkhorn_kernel(const float* __restrict__ Mg,
                float* __restrict__ Pg,
                float* __restrict__ part,    // [B_][G_][N_] partial sums
                float* __restrict__ vglob,   // [B_][N_]
                int* __restrict__ cnts)      // [B_ * 64] (256B-padded counters)
{
    extern __shared__ float lds[];
    float* Kl = lds;                    // RPB x KSTR
    float* vl = lds + RPB * KSTR;       // N_
    float* ul = vl + N_;                // RPB

    const int b    = blockIdx.x & (B_ - 1);
    const int g    = blockIdx.x >> 3;
    const int t    = threadIdx.x;
    const int row0 = g * RPB;
    const float r = 1.0f / (float)N_;
    const float c = 1.0f / (float)N_;

    float* partb = part + ((size_t)b * G_) * N_;   // this batch's 32 slots
    float* vb    = vglob + (size_t)b * N_;

    // ---- stage K rows into LDS ----
    const float* Mb = Mg + ((size_t)b * N_ + row0) * N_;
    for (int i = 0; i < RPB; ++i) {
        float4 m4 = ((const float4*)(Mb + (size_t)i * N_))[t];
        float4 k4;
        k4.x = expf(-LMB * fminf(m4.x, MAXD));
        k4.y = expf(-LMB * fminf(m4.y, MAXD));
        k4.z = expf(-LMB * fminf(m4.z, MAXD));
        k4.w = expf(-LMB * fminf(m4.w, MAXD));
        *(float4*)&Kl[i * KSTR + 4 * t] = k4;
    }
    if (t < RPB) ul[t] = r;             // u = r initially
    __syncthreads();

    int* cnt = cnts + b * 64;
    int tgt = 0;

    for (int it = 0; it <= NITER; ++it) {
        // ---- phase A: partial[j] = sum_{our rows i} K[i][j] * u_i ----
        float4 a = make_float4(0.f, 0.f, 0.f, 0.f);
#pragma unroll
        for (int i = 0; i < RPB; ++i) {
            const float u  = ul[i];
            const float4 k4 = *(const float4*)&Kl[i * KSTR + 4 * t];
            a.x = fmaf(k4.x, u, a.x);
            a.y = fmaf(k4.y, u, a.y);
            a.z = fmaf(k4.z, u, a.z);
            a.w = fmaf(k4.w, u, a.w);
        }
        *(float4*)&partb[(size_t)g * N_ + 4 * t] = a;   // private slot, no atomics

        batch_barrier(cnt, tgt += G_);

        // ---- owner reduce: block g owns columns [32g, 32g+32) ----
        if (t < G_) {
            const int j = row0 + t;
            float y = 0.f;
#pragma unroll
            for (int gp = 0; gp < G_; ++gp)             // 32 independent 128B
                y += partb[(size_t)gp * N_ + j];        // coalesced loads
            vb[j] = c / y;
        }

        batch_barrier(cnt, tgt += G_);

        // ---- broadcast: everyone loads full v into LDS ----
        float4 v4 = ((const float4*)vb)[t];
        ((float4*)vl)[t] = v4;
        __syncthreads();

        if (it == NITER) break;         // vl holds final v

        // ---- phase B: z_i = sum_j K[i][j] v_j ; u_i = r / z_i ----
        const int rI = t >> 3;          // 0..31 (row within block)
        const int l  = t & 7;           // 0..7  (8 lanes per row, same wave)
        float4 za = make_float4(0.f, 0.f, 0.f, 0.f);
#pragma unroll
        for (int k2 = 0; k2 < 32; ++k2) {
            const int j0 = 4 * l + 32 * k2;
            const float4 k4 = *(const float4*)&Kl[rI * KSTR + j0];
            const float4 vv = *(const float4*)&vl[j0];
            za.x = fmaf(k4.x, vv.x, za.x);
            za.y = fmaf(k4.y, vv.y, za.y);
            za.z = fmaf(k4.z, vv.z, za.z);
            za.w = fmaf(k4.w, vv.w, za.w);
        }
        float z = za.x + za.y + za.z + za.w;
        z += __shfl_xor(z, 1);
        z += __shfl_xor(z, 2);
        z += __shfl_xor(z, 4);
        if (l == 0) ul[rI] = r / z;
        __syncthreads();
    }

    // ---- epilogue: P[i][j] = u_i * K[i][j] * v_j ----
    float* Pb = Pg + ((size_t)b * N_ + row0) * N_;
    const float4 v4 = ((const float4*)vl)[t];
    for (int i = 0; i < RPB; ++i) {
        const float u  = ul[i];
        const float4 k4 = *(const float4*)&Kl[i * KSTR + 4 * t];
        float4 p4;
        p4.x = u * k4.x * v4.x;
        p4.y = u * k4.y * v4.y;
        p4.z = u * k4.z * v4.z;
        p4.w = u * k4.w * v4.w;
        ((float4*)(Pb + (size_t)i * N_))[t] = p4;
    }
}

extern "C" void kernel_launch(void* const* d_in, const int* in_sizes, int n_in,
                              void* d_out, int out_size, void* d_ws, size_t ws_size,
                              hipStream_t stream) {
    const float* M = (const float*)d_in[0];
    float* P = (float*)d_out;

    const size_t part_floats = (size_t)B_ * G_ * N_;   // 1 MB
    const size_t v_floats    = (size_t)B_ * N_;        // 32 KB
    float* part  = (float*)d_ws;
    float* vglob = part + part_floats;
    int*   cnts  = (int*)(vglob + v_floats);
    hipMemsetAsync(cnts, 0, (size_t)B_ * 64 * sizeof(int), stream);

    const size_t lds_bytes = (size_t)LDS_FLOATS * sizeof(float);
    (void)hipFuncSetAttribute((const void*)sinkhorn_kernel,
                              hipFuncAttributeMaxDynamicSharedMemorySize,
                              (int)lds_bytes);

    void* args[] = { (void*)&M, (void*)&P, (void*)&part, (void*)&vglob, (void*)&cnts };
    hipError_t e = hipLaunchCooperativeKernel((void*)sinkhorn_kernel,
                                              dim3(B_ * G_), dim3(TPB),
                                              args, (unsigned)lds_bytes, stream);
    if (e != hipSuccess) {
        // fallback: 256 blocks on 256 CUs with 1 block/CU is co-resident,
        // which the spin barriers require
        sinkhorn_kernel<<<dim3(B_ * G_), dim3(TPB), lds_bytes, stream>>>(
            M, P, part, vglob, cnts);
    }
}

// Round 3
// 1033.313 us; speedup vs baseline: 2.5079x; 2.5079x over previous
//
#include <hip/hip_runtime.h>
#include <math.h>

// Sinkhorn regularized transport, B=8, m=n=1024, fp32, 100 iterations.
//
// Round 3: fence-free global synchronization.
// Evidence from R1/R2: each batch_barrier with __threadfence cost ~12us
// (R1: 1 barrier/iter = 13us/iter; R2: 2 barriers/iter = 25us/iter).
// Agent-scope __threadfence on gfx950 emits buffer_wbl2/buffer_inv (full
// L2 writeback/invalidate); 32 blocks/XCD x 2 fences/iter thrashed L2.
//
// This version has ZERO cache-maintenance ops:
//  - All cross-block data (partials, flag counter) uses agent-scope RELAXED
//    atomics, which emit sc0 sc1 (bypass L1+L2, served by device-coherent L3).
//  - Ordering: __syncthreads() emits s_waitcnt vmcnt(0) before s_barrier,
//    so all waves' bypassing stores reached L3 before the flag add.
//  - ONE barrier per iteration: after the barrier, every block all-reads the
//    32 partial vectors (coalesced 8B agent loads) and computes full v
//    locally; phase B only needs block-local u, so no second sync.
//  - Partials double-buffered by iteration parity: buffer p is re-written at
//    it+2, which is after barrier it+1, which is after all blocks finished
//    reading buffer p (their reads precede their it+1 partial stores).

#define B_    8
#define N_    1024
#define G_    32          // blocks per batch
#define RPB   32          // rows per block
#define KSTR  1028        // LDS row stride (floats): 16B aligned, bank skew
#define NITER 100
#define TPB   256
#define LMB   10.0f
#define MAXD  5.0f

#define LDS_FLOATS (RPB * KSTR + N_ + RPB)

typedef unsigned long long u64;

__device__ __forceinline__ void st8_l3(float* p, float a, float b) {
    float2 f2 = make_float2(a, b);
    __hip_atomic_store((u64*)p, __builtin_bit_cast(u64, f2),
                       __ATOMIC_RELAXED, __HIP_MEMORY_SCOPE_AGENT);
}
__device__ __forceinline__ float2 ld8_l3(const float* p) {
    u64 raw = __hip_atomic_load((const u64*)p,
                                __ATOMIC_RELAXED, __HIP_MEMORY_SCOPE_AGENT);
    return __builtin_bit_cast(float2, raw);
}

// Fence-free per-batch barrier: no buffer_wbl2 / buffer_inv.
// __syncthreads() drains vmcnt(0) for every wave (bypassing stores are at
// the coherence point); flag add/poll are L3-point atomics; the exit branch
// depends on the poll load, ordering subsequent loads in hardware.
__device__ __forceinline__ void batch_barrier(int* cnt, int target) {
    __syncthreads();
    if (threadIdx.x == 0) {
        __atomic_signal_fence(__ATOMIC_SEQ_CST);
        __hip_atomic_fetch_add(cnt, 1, __ATOMIC_RELAXED, __HIP_MEMORY_SCOPE_AGENT);
        while (__hip_atomic_load(cnt, __ATOMIC_RELAXED,
                                 __HIP_MEMORY_SCOPE_AGENT) < target) {
            __builtin_amdgcn_s_sleep(2);
        }
        __atomic_signal_fence(__ATOMIC_SEQ_CST);
    }
    __syncthreads();
}

__global__ void __launch_bounds__(TPB, 1)
sinkhorn_kernel(const float* __restrict__ Mg,
                float* __restrict__ Pg,
                float* __restrict__ part,    // [2][B_][G_][N_] partials
                int* __restrict__ cnts)      // [B_ * 64] padded counters
{
    extern __shared__ float lds[];
    float* Kl = lds;                    // RPB x KSTR
    float* vl = lds + RPB * KSTR;       // N_
    float* ul = vl + N_;                // RPB

    const int b    = blockIdx.x & (B_ - 1);
    const int g    = blockIdx.x >> 3;
    const int t    = threadIdx.x;
    const int row0 = g * RPB;
    const float r = 1.0f / (float)N_;
    const float c = 1.0f / (float)N_;

    // ---- stage K rows into LDS ----
    const float* Mb = Mg + ((size_t)b * N_ + row0) * N_;
    for (int i = 0; i < RPB; ++i) {
        float4 m4 = ((const float4*)(Mb + (size_t)i * N_))[t];
        float4 k4;
        k4.x = expf(-LMB * fminf(m4.x, MAXD));
        k4.y = expf(-LMB * fminf(m4.y, MAXD));
        k4.z = expf(-LMB * fminf(m4.z, MAXD));
        k4.w = expf(-LMB * fminf(m4.w, MAXD));
        *(float4*)&Kl[i * KSTR + 4 * t] = k4;
    }
    if (t < RPB) ul[t] = r;             // u = r initially
    __syncthreads();

    int* cnt = cnts + b * 64;
    int tgt = 0;

    for (int it = 0; it <= NITER; ++it) {
        // ---- phase A: partial[j] = sum_{own rows i} K[i][j] * u_i ----
        float4 a = make_float4(0.f, 0.f, 0.f, 0.f);
#pragma unroll
        for (int i = 0; i < RPB; ++i) {
            const float u  = ul[i];
            const float4 k4 = *(const float4*)&Kl[i * KSTR + 4 * t];
            a.x = fmaf(k4.x, u, a.x);
            a.y = fmaf(k4.y, u, a.y);
            a.z = fmaf(k4.z, u, a.z);
            a.w = fmaf(k4.w, u, a.w);
        }
        float* slot = part + ((((size_t)(it & 1) * B_ + b) * G_ + g) * N_);
        st8_l3(&slot[4 * t],     a.x, a.y);
        st8_l3(&slot[4 * t + 2], a.z, a.w);

        batch_barrier(cnt, tgt += G_);

        // ---- all-read reduce (coalesced 8B L3 loads), v computed locally --
        const float* pb = part + (((size_t)(it & 1) * B_ + b) * G_) * N_;
        float2 y0 = make_float2(0.f, 0.f);
        float2 y1 = make_float2(0.f, 0.f);
#pragma unroll
        for (int gp = 0; gp < G_; ++gp) {
            float2 p0 = ld8_l3(&pb[(size_t)gp * N_ + 2 * t]);
            float2 p1 = ld8_l3(&pb[(size_t)gp * N_ + 512 + 2 * t]);
            y0.x += p0.x; y0.y += p0.y;
            y1.x += p1.x; y1.y += p1.y;
        }
        float2 v0 = make_float2(c / y0.x, c / y0.y);
        float2 v1 = make_float2(c / y1.x, c / y1.y);
        *(float2*)&vl[2 * t]       = v0;
        *(float2*)&vl[512 + 2 * t] = v1;
        __syncthreads();

        if (it == NITER) break;         // vl holds final v

        // ---- phase B: z_i = sum_j K[i][j] v_j ; u_i = r / z_i ----
        const int rI = t >> 3;          // 0..31 (row within block)
        const int l  = t & 7;           // 0..7  (8 lanes per row, same wave)
        float4 za = make_float4(0.f, 0.f, 0.f, 0.f);
#pragma unroll
        for (int k2 = 0; k2 < 32; ++k2) {
            const int j0 = 4 * l + 32 * k2;
            const float4 k4 = *(const float4*)&Kl[rI * KSTR + j0];
            const float4 vv = *(const float4*)&vl[j0];
            za.x = fmaf(k4.x, vv.x, za.x);
            za.y = fmaf(k4.y, vv.y, za.y);
            za.z = fmaf(k4.z, vv.z, za.z);
            za.w = fmaf(k4.w, vv.w, za.w);
        }
        float z = za.x + za.y + za.z + za.w;
        z += __shfl_xor(z, 1);
        z += __shfl_xor(z, 2);
        z += __shfl_xor(z, 4);
        if (l == 0) ul[rI] = r / z;
        __syncthreads();
    }

    // ---- epilogue: P[i][j] = u_i * K[i][j] * v_j ----
    float* Pb = Pg + ((size_t)b * N_ + row0) * N_;
    const float4 v4 = *(const float4*)&vl[4 * t];
    for (int i = 0; i < RPB; ++i) {
        const float u  = ul[i];
        const float4 k4 = *(const float4*)&Kl[i * KSTR + 4 * t];
        float4 p4;
        p4.x = u * k4.x * v4.x;
        p4.y = u * k4.y * v4.y;
        p4.z = u * k4.z * v4.z;
        p4.w = u * k4.w * v4.w;
        ((float4*)(Pb + (size_t)i * N_))[t] = p4;
    }
}

extern "C" void kernel_launch(void* const* d_in, const int* in_sizes, int n_in,
                              void* d_out, int out_size, void* d_ws, size_t ws_size,
                              hipStream_t stream) {
    const float* M = (const float*)d_in[0];
    float* P = (float*)d_out;

    const size_t part_floats = (size_t)2 * B_ * G_ * N_;   // 2 MB
    float* part = (float*)d_ws;
    int*   cnts = (int*)(part + part_floats);
    hipMemsetAsync(cnts, 0, (size_t)B_ * 64 * sizeof(int), stream);

    const size_t lds_bytes = (size_t)LDS_FLOATS * sizeof(float);
    (void)hipFuncSetAttribute((const void*)sinkhorn_kernel,
                              hipFuncAttributeMaxDynamicSharedMemorySize,
                              (int)lds_bytes);

    void* args[] = { (void*)&M, (void*)&P, (void*)&part, (void*)&cnts };
    hipError_t e = hipLaunchCooperativeKernel((void*)sinkhorn_kernel,
                                              dim3(B_ * G_), dim3(TPB),
                                              args, (unsigned)lds_bytes, stream);
    if (e != hipSuccess) {
        // fallback: 256 blocks at 1 block/CU on 256 CUs is co-resident,
        // which the spin barriers require
        sinkhorn_kernel<<<dim3(B_ * G_), dim3(TPB), lds_bytes, stream>>>(
            M, P, part, cnts);
    }
}

// Round 4
// 618.086 us; speedup vs baseline: 4.1926x; 1.6718x over previous
//
#include <hip/hip_runtime.h>
#include <math.h>

// Sinkhorn regularized transport, B=8, m=n=1024, fp32, 100 iterations.
//
// Round 4: distributed stamp-flag dataflow, owner-reduce + broadcast.
// R3 evidence: 9.5us/iter with only ~0.9us VALU. Costs: central-counter RMW
// serialization (32 blocks, 1 line), and the all-read reduce (128KB/block/iter
// through ~550cyc L3 with shallow load pipeline). This version:
//  - No central counter. Each block publishes a per-block iteration stamp
//    (distinct dwords, zero RMW contention) after __syncthreads() drains its
//    partial stores to the L3 coherence point (sc0 sc1 bypassing atomics,
//    mechanism validated in R3).
//  - Owner-reduce: block g owns cols [32g,32g+32): polls 32 stamps with one
//    coalesced 128B wave-load, reads 4KB of partials (coalesced), reduces via
//    wave shuffles, publishes 128B of v + stamp. Consumers read 4KB of v.
//    Per-block L3 traffic: 8KB/iter vs 128KB in R3 (16x less).
//  - Everything double-buffered by iteration parity; stamps are monotonic
//    iteration numbers so no reset is ever needed.

#define B_    8
#define N_    1024
#define G_    32          // blocks per batch
#define RPB   32          // rows per block
#define KSTR  1028        // LDS row stride (floats): 16B aligned, bank skew
#define NITER 100
#define TPB   256
#define LMB   10.0f
#define MAXD  5.0f

// LDS: Kl (RPB*KSTR) + vl (N_) + ul (RPB) + red (G_ float4)
#define LDS_FLOATS (RPB * KSTR + N_ + RPB + 4 * G_)

typedef unsigned long long u64;

__device__ __forceinline__ void st8(float* p, float a, float b) {
    float2 f2 = make_float2(a, b);
    __hip_atomic_store((u64*)p, __builtin_bit_cast(u64, f2),
                       __ATOMIC_RELAXED, __HIP_MEMORY_SCOPE_AGENT);
}
__device__ __forceinline__ float2 ld8(const float* p) {
    u64 raw = __hip_atomic_load((const u64*)p,
                                __ATOMIC_RELAXED, __HIP_MEMORY_SCOPE_AGENT);
    return __builtin_bit_cast(float2, raw);
}
__device__ __forceinline__ void publish(int* s, int v) {
    __atomic_signal_fence(__ATOMIC_SEQ_CST);
    __hip_atomic_store(s, v, __ATOMIC_RELAXED, __HIP_MEMORY_SCOPE_AGENT);
}
// Wait until all 32 stamps reach tgt. One coalesced 128B wave-load per poll
// (lanes duplicate the 32 stamps twice across the 64-lane vote).
__device__ __forceinline__ void poll32(const int* st, int tgt) {
    const int l = threadIdx.x & 31;
    for (;;) {
        int s = __hip_atomic_load(&st[l], __ATOMIC_RELAXED,
                                  __HIP_MEMORY_SCOPE_AGENT);
        if (__all(s >= tgt)) break;
        __builtin_amdgcn_s_sleep(2);
    }
    __atomic_signal_fence(__ATOMIC_SEQ_CST);
}

__global__ void __launch_bounds__(TPB, 1)
sinkhorn_kernel(const float* __restrict__ Mg,
                float* __restrict__ Pg,
                float* __restrict__ part,    // [2][B_][G_][N_]
                float* __restrict__ vbuf,    // [2][B_][N_]
                int* __restrict__ stA,       // [2][B_][G_]
                int* __restrict__ stV)       // [2][B_][G_]
{
    extern __shared__ float lds[];
    float* Kl   = lds;                        // RPB x KSTR
    float* vl   = lds + RPB * KSTR;           // N_
    float* ul   = vl + N_;                    // RPB
    float4* red = (float4*)(ul + RPB);        // G_ float4 (16B-aligned)

    const int b    = blockIdx.x & (B_ - 1);
    const int g    = blockIdx.x >> 3;
    const int t    = threadIdx.x;
    const int row0 = g * RPB;
    const float r = 1.0f / (float)N_;
    const float c = 1.0f / (float)N_;

    // ---- stage K rows into LDS ----
    const float* Mb = Mg + ((size_t)b * N_ + row0) * N_;
    for (int i = 0; i < RPB; ++i) {
        float4 m4 = ((const float4*)(Mb + (size_t)i * N_))[t];
        float4 k4;
        k4.x = expf(-LMB * fminf(m4.x, MAXD));
        k4.y = expf(-LMB * fminf(m4.y, MAXD));
        k4.z = expf(-LMB * fminf(m4.z, MAXD));
        k4.w = expf(-LMB * fminf(m4.w, MAXD));
        *(float4*)&Kl[i * KSTR + 4 * t] = k4;
    }
    if (t < RPB) ul[t] = r;             // u = r initially
    __syncthreads();

    for (int it = 0; it <= NITER; ++it) {
        const int p   = it & 1;
        const int tgt = it + 1;
        int* stA_pb = stA + ((size_t)p * B_ + b) * G_;
        int* stV_pb = stV + ((size_t)p * B_ + b) * G_;

        // ---- phase A: partial[j] = sum_{own rows i} K[i][j] * u_i ----
        float4 a = make_float4(0.f, 0.f, 0.f, 0.f);
#pragma unroll
        for (int i = 0; i < RPB; ++i) {
            const float u  = ul[i];
            const float4 k4 = *(const float4*)&Kl[i * KSTR + 4 * t];
            a.x = fmaf(k4.x, u, a.x);
            a.y = fmaf(k4.y, u, a.y);
            a.z = fmaf(k4.z, u, a.z);
            a.w = fmaf(k4.w, u, a.w);
        }
        float* slot = part + (((size_t)p * B_ + b) * G_ + g) * N_;
        st8(&slot[4 * t],     a.x, a.y);
        st8(&slot[4 * t + 2], a.z, a.w);

        __syncthreads();                     // drain all waves' stores to L3
        if (t == 0) publish(&stA_pb[g], tgt);

        // ---- owner-reduce: block g owns cols [32g, 32g+32) ----
        poll32(stA_pb, tgt);
        {
            const int gp = t >> 3;           // producer 0..31
            const int q  = t & 7;            // col quad within our slice
            const float* pb = part + (((size_t)p * B_ + b) * G_ + gp) * N_
                            + 32 * g + 4 * q;
            float2 s0 = ld8(pb);
            float2 s1 = ld8(pb + 2);
            float4 acc = make_float4(s0.x, s0.y, s1.x, s1.y);
            // reduce across the wave's 8 producers (lane bits 3..5)
#pragma unroll
            for (int d = 8; d <= 32; d <<= 1) {
                acc.x += __shfl_xor(acc.x, d);
                acc.y += __shfl_xor(acc.y, d);
                acc.z += __shfl_xor(acc.z, d);
                acc.w += __shfl_xor(acc.w, d);
            }
            const int wv = t >> 6;
            if ((t & 63) < 8) red[wv * 8 + (t & 63)] = acc;
        }
        __syncthreads();
        float* vb = vbuf + ((size_t)p * B_ + b) * N_;
        if (t < 8) {
            float4 y4;
            y4.x = red[t].x + red[8 + t].x + red[16 + t].x + red[24 + t].x;
            y4.y = red[t].y + red[8 + t].y + red[16 + t].y + red[24 + t].y;
            y4.z = red[t].z + red[8 + t].z + red[16 + t].z + red[24 + t].z;
            y4.w = red[t].w + red[8 + t].w + red[16 + t].w + red[24 + t].w;
            st8(&vb[32 * g + 4 * t],     c / y4.x, c / y4.y);
            st8(&vb[32 * g + 4 * t + 2], c / y4.z, c / y4.w);
        }
        if (t == 0) {
            __atomic_signal_fence(__ATOMIC_SEQ_CST);
            __builtin_amdgcn_s_waitcnt(0);   // wave-0's v stores at L3
            publish(&stV_pb[g], tgt);
        }

        // ---- broadcast: everyone reads full v (4KB) into LDS ----
        poll32(stV_pb, tgt);
        {
            float2 w0 = ld8(&vb[4 * t]);
            float2 w1 = ld8(&vb[4 * t + 2]);
            *(float4*)&vl[4 * t] = make_float4(w0.x, w0.y, w1.x, w1.y);
        }
        __syncthreads();

        if (it == NITER) break;              // vl holds final v

        // ---- phase B: z_i = sum_j K[i][j] v_j ; u_i = r / z_i ----
        const int rI = t >> 3;               // 0..31 (row within block)
        const int l  = t & 7;                // 0..7  (8 lanes per row)
        float4 za = make_float4(0.f, 0.f, 0.f, 0.f);
#pragma unroll
        for (int k2 = 0; k2 < 32; ++k2) {
            const int j0 = 4 * l + 32 * k2;
            const float4 k4 = *(const float4*)&Kl[rI * KSTR + j0];
            const float4 vv = *(const float4*)&vl[j0];
            za.x = fmaf(k4.x, vv.x, za.x);
            za.y = fmaf(k4.y, vv.y, za.y);
            za.z = fmaf(k4.z, vv.z, za.z);
            za.w = fmaf(k4.w, vv.w, za.w);
        }
        float z = za.x + za.y + za.z + za.w;
        z += __shfl_xor(z, 1);
        z += __shfl_xor(z, 2);
        z += __shfl_xor(z, 4);
        if (l == 0) ul[rI] = r / z;
        __syncthreads();
    }

    // ---- epilogue: P[i][j] = u_i * K[i][j] * v_j ----
    float* Pb = Pg + ((size_t)b * N_ + row0) * N_;
    const float4 v4 = *(const float4*)&vl[4 * t];
    for (int i = 0; i < RPB; ++i) {
        const float u  = ul[i];
        const float4 k4 = *(const float4*)&Kl[i * KSTR + 4 * t];
        float4 p4;
        p4.x = u * k4.x * v4.x;
        p4.y = u * k4.y * v4.y;
        p4.z = u * k4.z * v4.z;
        p4.w = u * k4.w * v4.w;
        ((float4*)(Pb + (size_t)i * N_))[t] = p4;
    }
}

extern "C" void kernel_launch(void* const* d_in, const int* in_sizes, int n_in,
                              void* d_out, int out_size, void* d_ws, size_t ws_size,
                              hipStream_t stream) {
    const float* M = (const float*)d_in[0];
    float* P = (float*)d_out;

    const size_t part_floats = (size_t)2 * B_ * G_ * N_;   // 2 MB
    const size_t v_floats    = (size_t)2 * B_ * N_;        // 64 KB
    float* part = (float*)d_ws;
    float* vbuf = part + part_floats;
    int*   stA  = (int*)(vbuf + v_floats);
    int*   stV  = stA + 2 * B_ * G_;
    hipMemsetAsync(stA, 0, (size_t)4 * B_ * G_ * sizeof(int), stream);

    const size_t lds_bytes = (size_t)LDS_FLOATS * sizeof(float);
    (void)hipFuncSetAttribute((const void*)sinkhorn_kernel,
                              hipFuncAttributeMaxDynamicSharedMemorySize,
                              (int)lds_bytes);

    void* args[] = { (void*)&M, (void*)&P, (void*)&part, (void*)&vbuf,
                     (void*)&stA, (void*)&stV };
    hipError_t e = hipLaunchCooperativeKernel((void*)sinkhorn_kernel,
                                              dim3(B_ * G_), dim3(TPB),
                                              args, (unsigned)lds_bytes, stream);
    if (e != hipSuccess) {
        // fallback: 256 blocks at 1 block/CU on 256 CUs is co-resident,
        // which the stamp-flag dataflow requires
        sinkhorn_kernel<<<dim3(B_ * G_), dim3(TPB), lds_bytes, stream>>>(
            M, P, part, vbuf, stA, stV);
    }
}